// Round 1
// baseline (176.410 us; speedup 1.0000x reference)
//
#include <hip/hip_runtime.h>
#include <math.h>

// LayerSumSimple: K-level chained cummax-of-sums == max-plus affine scan with
// 8-element state s:  s[k] <- max(s[k], s[k-1] + g_k(t)),  g_k = x*w[k]+b[k].
// Round-7 restructure: L=128 chunks (C=64) and a SINGLE serial pass2 kernel
// that scans all 64 chunk maps per batch and emits chunk inflows directly.
//   - halves summary volume (37.7 -> 18.9 MB) and infl (8.4 -> 4.2 MB)
//   - deletes gsum/ginfl and the second full re-read of sum (pass2c)
//   - 3 launches instead of 5 (fewer dispatch gaps, shorter serial chain)
// All workspace arrays use PLANE layout: plane i of region r at
// base[r*NPLANES*DD + i*DD + d] -> lane d accesses are fully coalesced.
namespace {
constexpr int BB   = 8;
constexpr int TT   = 8192;
constexpr int DD   = 256;
constexpr int KK   = 8;
constexpr int TOUT = TT - KK + 1;       // 8185
constexpr int NSUM = 36;                // 8 c-vec + 28 strict-lower A
constexpr int C    = 64;                // chunks per sequence (was 128)
constexpr int L    = TT / C;            // 128 steps per chunk
constexpr int U    = 8;                 // pipeline batch (steps)
constexpr int NB   = L / U;             // 16 batches per chunk

// strict-lower-triangle linear index: k in [1,8), j < k  ->  [0,28)
__host__ __device__ __forceinline__ constexpr int alin(int k, int j) {
    return k * (k - 1) / 2 + j;
}
// plane index of A[k][j] in the 36-plane map layout (planes 0..7 = c-vec)
__host__ __device__ __forceinline__ constexpr int tri(int k, int j) {
    return 8 + alin(k, j);
}

// one time-step of the summary recurrence (descending k uses OLD row k-1).
// a[] is the strict-lower triangle of the accumulated max-plus map (28 live
// registers, flat so the allocator never materializes the dead upper half).
__device__ __forceinline__ void step_sum(float x, const float (&wk)[KK],
                                         const float (&bk)[KK],
                                         float (&a)[28], float (&cv)[KK])
{
    float g[KK];
    #pragma unroll
    for (int k = 0; k < KK; ++k) g[k] = fmaf(x, wk[k], bk[k]);
    #pragma unroll
    for (int k = KK - 1; k >= 2; --k) {
        #pragma unroll
        for (int j = 0; j < k - 1; ++j)
            a[alin(k, j)] = fmaxf(a[alin(k, j)], g[k] + a[alin(k - 1, j)]);
        a[alin(k, k - 1)] = fmaxf(a[alin(k, k - 1)], g[k]);  // diag of row k-1 == 0
        cv[k] = fmaxf(cv[k], g[k] + cv[k - 1]);              // OLD cv[k-1]
    }
    a[alin(1, 0)] = fmaxf(a[alin(1, 0)], g[1]);
    cv[1] = fmaxf(cv[1], g[1] + cv[0]);
    cv[0] = fmaxf(cv[0], g[0]);
}

// ---- pass 1: one block per (b, chunk); thread d = channel ----
__global__ __launch_bounds__(256) void pass1_summaries(
    const float* __restrict__ X, const float* __restrict__ W,
    const float* __restrict__ Bv, float* __restrict__ sum)
{
    const int b = blockIdx.x / C;
    const int c = blockIdx.x % C;
    const int d = threadIdx.x;

    float wk[KK], bk[KK];
    #pragma unroll
    for (int k = 0; k < KK; ++k) { wk[k] = W[k * DD + d]; bk[k] = Bv[k * DD + d]; }

    float cv[KK];
    float a[28];
    #pragma unroll
    for (int k = 0; k < KK; ++k) cv[k] = -INFINITY;
    #pragma unroll
    for (int i = 0; i < 28; ++i) a[i] = -INFINITY;

    const float* xp = X + ((size_t)(b * TT + c * L)) * DD + d;
    float x0[U], x1[U];
    #pragma unroll
    for (int u = 0; u < U; ++u) x0[u] = xp[u * DD];

    // dynamic loop: 16-step body fits I$; prefetch distance = 8 steps
    #pragma unroll 1
    for (int ib = 0; ib + 2 < NB; ib += 2) {
        #pragma unroll
        for (int u = 0; u < U; ++u) x1[u] = xp[(U + u) * DD];
        #pragma unroll
        for (int u = 0; u < U; ++u) step_sum(x0[u], wk, bk, a, cv);
        #pragma unroll
        for (int u = 0; u < U; ++u) x0[u] = xp[(2 * U + u) * DD];
        #pragma unroll
        for (int u = 0; u < U; ++u) step_sum(x1[u], wk, bk, a, cv);
        xp += 2 * U * DD;
    }
    // tail: batches NB-2 (in x0) and NB-1
    #pragma unroll
    for (int u = 0; u < U; ++u) x1[u] = xp[(U + u) * DD];
    #pragma unroll
    for (int u = 0; u < U; ++u) step_sum(x0[u], wk, bk, a, cv);
    #pragma unroll
    for (int u = 0; u < U; ++u) step_sum(x1[u], wk, bk, a, cv);

    // plane-layout store: 36 coalesced 1KB stores
    float* sp = sum + (size_t)blockIdx.x * NSUM * DD + d;   // region = b*C + c
    #pragma unroll
    for (int k = 0; k < KK; ++k) sp[k * DD] = cv[k];
    #pragma unroll
    for (int i = 0; i < 28; ++i) sp[(8 + i) * DD] = a[i];
}

// plane-layout map load: 36 coalesced scalar loads into registers
__device__ __forceinline__ void ld_map(const float* __restrict__ p,
                                       float (&m)[NSUM])
{
    #pragma unroll
    for (int i = 0; i < NSUM; ++i) m[i] = p[i * DD];
}

// s <- apply(map m, s)
__device__ __forceinline__ void apply_map(const float (&m)[NSUM], float (&s)[KK])
{
    float ns[KK];
    #pragma unroll
    for (int k = 0; k < KK; ++k) ns[k] = fmaxf(m[k], s[k]);   // c[k], diag
    #pragma unroll
    for (int k = 1; k < KK; ++k) {
        #pragma unroll
        for (int j = 0; j < k; ++j) ns[k] = fmaxf(ns[k], m[tri(k, j)] + s[j]);
    }
    #pragma unroll
    for (int k = 0; k < KK; ++k) s[k] = ns[k];
}

// ---- pass 2: one block per b; serial apply over all C chunk maps,
//      emitting the inflow state BEFORE each chunk (double-buffered loads) ----
__global__ __launch_bounds__(256) void pass2_scan_chunks(
    const float* __restrict__ sum, float* __restrict__ infl)
{
    const int b = blockIdx.x;
    const int d = threadIdx.x;

    float s[KK];
    #pragma unroll
    for (int k = 0; k < KK; ++k) s[k] = -INFINITY;

    const float* mp = sum + (size_t)b * C * NSUM * DD + d;
    float* ip = infl + (size_t)b * C * KK * DD + d;
    float m0[NSUM], m1[NSUM];
    ld_map(mp, m0);
    #pragma unroll 1
    for (int ci = 0; ci + 2 < C; ci += 2) {
        ld_map(mp + NSUM * DD, m1);
        #pragma unroll
        for (int k = 0; k < KK; ++k) ip[k * DD] = s[k];      // inflow BEFORE ci
        apply_map(m0, s);
        ld_map(mp + 2 * NSUM * DD, m0);
        #pragma unroll
        for (int k = 0; k < KK; ++k) ip[KK * DD + k * DD] = s[k];
        apply_map(m1, s);
        mp += 2 * NSUM * DD;
        ip += 2 * KK * DD;
    }
    ld_map(mp + NSUM * DD, m1);
    #pragma unroll
    for (int k = 0; k < KK; ++k) ip[k * DD] = s[k];
    apply_map(m0, s);
    #pragma unroll
    for (int k = 0; k < KK; ++k) ip[KK * DD + k * DD] = s[k];
    apply_map(m1, s);
}

// ---- pass 3: one block per (b, chunk); scan from inflow, emit outputs ----
__device__ __forceinline__ void step_scan(float x, const float (&wk)[KK],
                                          const float (&bk)[KK], float (&s)[KK])
{
    float g[KK];
    #pragma unroll
    for (int k = 0; k < KK; ++k) g[k] = fmaf(x, wk[k], bk[k]);
    #pragma unroll
    for (int k = KK - 1; k >= 1; --k) s[k] = fmaxf(s[k], s[k - 1] + g[k]);
    s[0] = fmaxf(s[0], g[0]);
}

__global__ __launch_bounds__(256) void pass3_scan(
    const float* __restrict__ X, const float* __restrict__ W,
    const float* __restrict__ Bv, const float* __restrict__ infl,
    float* __restrict__ out)
{
    const int b = blockIdx.x / C;
    const int c = blockIdx.x % C;
    const int d = threadIdx.x;

    float wk[KK], bk[KK];
    #pragma unroll
    for (int k = 0; k < KK; ++k) { wk[k] = W[k * DD + d]; bk[k] = Bv[k * DD + d]; }

    float s[KK];
    {
        const float* ip = infl + (size_t)blockIdx.x * KK * DD + d;  // region = b*C+c
        #pragma unroll
        for (int k = 0; k < KK; ++k) s[k] = ip[k * DD];
    }

    const int t0 = c * L;
    const float* xp = X + ((size_t)(b * TT + t0)) * DD + d;
    // base indexed by cumulative in-chunk step t only (op never advances)
    float* op = out + (size_t)b * TOUT * DD + (size_t)(t0 - (KK - 1)) * DD + d;

    float x0[U], x1[U];
    #pragma unroll
    for (int u = 0; u < U; ++u) x0[u] = xp[u * DD];

    int t = 0;                                   // step within chunk
    #pragma unroll 1
    for (int ib = 0; ib + 2 < NB; ib += 2) {
        #pragma unroll
        for (int u = 0; u < U; ++u) x1[u] = xp[(U + u) * DD];
        #pragma unroll
        for (int u = 0; u < U; ++u) {
            step_scan(x0[u], wk, bk, s);
            if (t0 + t >= KK - 1) op[t * DD] = s[KK - 1];
            ++t;
        }
        #pragma unroll
        for (int u = 0; u < U; ++u) x0[u] = xp[(2 * U + u) * DD];
        #pragma unroll
        for (int u = 0; u < U; ++u) {
            step_scan(x1[u], wk, bk, s);
            if (t0 + t >= KK - 1) op[t * DD] = s[KK - 1];
            ++t;
        }
        xp += 2 * U * DD;
    }
    #pragma unroll
    for (int u = 0; u < U; ++u) x1[u] = xp[(U + u) * DD];
    #pragma unroll
    for (int u = 0; u < U; ++u) {
        step_scan(x0[u], wk, bk, s);
        if (t0 + t >= KK - 1) op[t * DD] = s[KK - 1];
        ++t;
    }
    #pragma unroll
    for (int u = 0; u < U; ++u) {
        step_scan(x1[u], wk, bk, s);
        if (t0 + t >= KK - 1) op[t * DD] = s[KK - 1];
        ++t;
    }
}
} // namespace

extern "C" void kernel_launch(void* const* d_in, const int* in_sizes, int n_in,
                              void* d_out, int out_size, void* d_ws, size_t ws_size,
                              hipStream_t stream)
{
    const float* X  = (const float*)d_in[0];
    const float* W  = (const float*)d_in[1];
    const float* Bv = (const float*)d_in[2];
    float* out = (float*)d_out;

    // ws: sum 18.9 MB + infl 4.2 MB = 23.1 MB
    float* sum  = (float*)d_ws;
    float* infl = sum + (size_t)BB * C * NSUM * DD;

    pass1_summaries<<<BB * C, 256, 0, stream>>>(X, W, Bv, sum);
    pass2_scan_chunks<<<BB, 256, 0, stream>>>(sum, infl);
    pass3_scan<<<BB * C, 256, 0, stream>>>(X, W, Bv, infl, out);
}